// Round 8
// baseline (228.791 us; speedup 1.0000x reference)
//
#include <hip/hip_runtime.h>
#include <hip/hip_fp16.h>

#define NQ 20

__device__ __forceinline__ float bcast_first(float x) {
    return __int_as_float(__builtin_amdgcn_readfirstlane(__float_as_int(x)));
}

// RX butterfly, symmetric form: new = C*mine + SV*(partner.im, -partner.re)
__device__ __forceinline__ void bfly(float C, float SV, float2& a, float2& b) {
    float2 na = make_float2(C * a.x + SV * b.y, C * a.y - SV * b.x);
    float2 nb = make_float2(C * b.x + SV * a.y, C * b.y - SV * a.x);
    a = na; b = nb;
}

// vectorized over two complex packed in float4 (same butterfly both halves)
__device__ __forceinline__ void bfly4(float C, float SV, float4& a, float4& b) {
    float4 na = make_float4(C*a.x + SV*b.y, C*a.y - SV*b.x, C*a.z + SV*b.w, C*a.w - SV*b.z);
    float4 nb = make_float4(C*b.x + SV*a.y, C*b.y - SV*a.x, C*b.z + SV*a.w, C*b.w - SV*a.z);
    a = na; b = nb;
}

__device__ __forceinline__ unsigned int pack_h2(float re, float im) {
    __half2 h = __floats2half2_rn(re, im);
    return *(unsigned int*)&h;
}
__device__ __forceinline__ float2 unpack_h2(unsigned int u) {
    return __half22float2(*(__half2*)&u);
}

// swizzled LDS index for pass1: XOR bits 2..4 by bits 7..9 of the local index
__device__ __forceinline__ int swz1(int l) { return l ^ (((l >> 7) & 7) << 2); }

// ---------------------------------------------------------------------------
// Trig table: cos/sin of thetas/2 for all B*NQ angles, computed once.
// (Proven win R7: removes 18-22 unhidden libm calls per block prologue.)
// ---------------------------------------------------------------------------
__global__ void rx_trig(const float* __restrict__ thetas, float2* __restrict__ tab) {
    int i = threadIdx.x;
    if (i < 16 * NQ) {
        float th = 0.5f * thetas[i];
        tab[i] = make_float2(cosf(th), sinf(th));
    }
}

// ---------------------------------------------------------------------------
// Pass 1 (in-place fp32 global, fp16 LDS): bits 0..10 (qubits 19..9).
// One wave owns 2048 contiguous cpx. LDS = 2048 half2 = 8 KiB -> ~16-20
// blocks/CU (was 10 at fp32). Registers stay fp32; 2 fp16 roundings.
// ---------------------------------------------------------------------------
__global__ __launch_bounds__(64) void rx_p1(
        const float* __restrict__ phi, const float2* __restrict__ tab,
        float2* __restrict__ out) {
    __shared__ unsigned int lds[2048];              // 8 KiB
    const int lane = threadIdx.x;
    const int W = blockIdx.x;                       // [0, 8192)
    const int b = W >> 9;
    const int base = (W & 511) << 11;
    const float* ph = phi + ((size_t)b << NQ) + base;
    float2* op = out + ((size_t)b << NQ) + base;

    float c[11], sv[11];
#pragma unroll
    for (int beta = 0; beta < 11; ++beta) {
        float2 t = tab[b * NQ + (NQ - 1 - beta)];
        c[beta]  = bcast_first(t.x);
        sv[beta] = bcast_first(t.y);
    }

    float2 v[32];
#pragma unroll
    for (int k4 = 0; k4 < 8; ++k4) {
        float4 t = *(const float4*)(ph + (k4 << 8) + (lane << 2));
        v[k4 * 4 + 0] = make_float2(t.x, 0.f);
        v[k4 * 4 + 1] = make_float2(t.y, 0.f);
        v[k4 * 4 + 2] = make_float2(t.z, 0.f);
        v[k4 * 4 + 3] = make_float2(t.w, 0.f);
    }

    // stage 1: reg bits {0,1,8,9,10}
    const int regbit1[5]  = {0, 1, 8, 9, 10};
    const int regmask1[5] = {1, 2, 4, 8, 16};
#pragma unroll
    for (int t = 0; t < 5; ++t) {
        const float C = c[regbit1[t]], SV = sv[regbit1[t]];
        const int m = regmask1[t];
#pragma unroll
        for (int r = 0; r < 32; ++r)
            if (!(r & m)) bfly(C, SV, v[r], v[r | m]);
    }

    // exchange 1: pack 4 cpx -> uint4 (16 B) per k4
#pragma unroll
    for (int k4 = 0; k4 < 8; ++k4) {
        int s0 = swz1((k4 << 8) + (lane << 2));
        uint4 pk;
        pk.x = pack_h2(v[k4*4+0].x, v[k4*4+0].y);
        pk.y = pack_h2(v[k4*4+1].x, v[k4*4+1].y);
        pk.z = pack_h2(v[k4*4+2].x, v[k4*4+2].y);
        pk.w = pack_h2(v[k4*4+3].x, v[k4*4+3].y);
        *(uint4*)&lds[s0] = pk;
    }
    __syncthreads();

    // stage 2: reg bits 2..6 (each thread owns a disjoint LDS set: no barrier
    // needed between its own read-back and write-back)
    const int g = lane >> 2, lam = lane & 3;
#pragma unroll
    for (int r = 0; r < 32; ++r)
        v[r] = unpack_h2(lds[swz1((g << 7) | (r << 2) | lam)]);
#pragma unroll
    for (int t = 0; t < 5; ++t) {
        const float C = c[2 + t], SV = sv[2 + t];
        const int m = 1 << t;
#pragma unroll
        for (int r = 0; r < 32; ++r)
            if (!(r & m)) bfly(C, SV, v[r], v[r | m]);
    }
#pragma unroll
    for (int r = 0; r < 32; ++r)
        lds[swz1((g << 7) | (r << 2) | lam)] = pack_h2(v[r].x, v[r].y);
    __syncthreads();

    // stage 3 (R7 dense mapping): bit 7 pairs (m, m+1); lane-consecutive cpx
    float4 u[16];
#pragma unroll
    for (int m = 0; m < 16; ++m) {
        int l0 = (lane << 1) | ((m & 1) << 7) | (((m >> 1) & 1) << 8)
               | (((m >> 2) & 1) << 9) | (((m >> 3) & 1) << 10);
        uint2 t2 = *(uint2*)&lds[swz1(l0)];
        float2 a = unpack_h2(t2.x), bb = unpack_h2(t2.y);
        u[m] = make_float4(a.x, a.y, bb.x, bb.y);
    }
    {
        const float C = c[7], SV = sv[7];
#pragma unroll
        for (int m = 0; m < 16; m += 2)
            bfly4(C, SV, u[m], u[m + 1]);
    }
#pragma unroll
    for (int m = 0; m < 16; ++m) {
        int l0 = (lane << 1) | ((m & 1) << 7) | (((m >> 1) & 1) << 8)
               | (((m >> 2) & 1) << 9) | (((m >> 3) & 1) << 10);
        *(float4*)(op + l0) = u[m];                 // 1 KB contiguous per instr
    }
}

// ---------------------------------------------------------------------------
// Pass 2 (in-place fp32 global, fp16 LDS): bits 11..19 (qubits 8..0).
// Tile = 512 h x 16 lows as half2 = 32 KiB -> 5 blocks/CU (was 2 at fp32).
// Structure + ppair swizzle identical to R1's correctness-proven pass2_h;
// only the global ends are fp32 (in-place on out, L3-resident).
// ---------------------------------------------------------------------------
__device__ __forceinline__ int ppair(int h, int q) {
    return (h << 4) + (((q ^ (h & 7) ^ ((h >> 3) & 7)) & 7) << 1);
}

__global__ __launch_bounds__(256) void rx_p2(
        const float2* __restrict__ tab, float2* __restrict__ out) {
    __shared__ unsigned int buf[8192];              // 32 KiB
    const int tid = threadIdx.x;
    const int b = blockIdx.x >> 7;
    const int lb = blockIdx.x & 127;
    float2* p = out + ((size_t)b << NQ) + (lb << 4);

    // h-bit i <-> qubit 8-i
    float c[9], sv[9];
#pragma unroll
    for (int i = 0; i < 9; ++i) {
        float2 t = tab[b * NQ + (8 - i)];
        c[i]  = bcast_first(t.x);
        sv[i] = bcast_first(t.y);
    }

    // Stage A: fp32 global -> fp16 LDS, 128B-chunk coalesced reads
#pragma unroll
    for (int i = 0; i < 16; ++i) {
        int f = (i << 8) | tid;                     // [0, 4096)
        int h = f >> 3, j = f & 7;                  // row, cpx-pair
        float4 t = *(const float4*)(p + h * 2048 + (j << 1));
        uint2 pk;
        pk.x = pack_h2(t.x, t.y);
        pk.y = pack_h2(t.z, t.w);
        *(uint2*)&buf[ppair(h, j)] = pk;
    }
    __syncthreads();

    // Stage B2: h bits 5..8 (qubits 3..0), regs m in [0,16), vectorized low-pair
    {
        const int hl = tid & 31;                    // h bits 0..4
        const int j  = tid >> 5;                    // low pair [0,8)
        float4 w[16];
#pragma unroll
        for (int m = 0; m < 16; ++m) {
            int h = (m << 5) | hl;
            uint2 t = *(const uint2*)&buf[ppair(h, j)];
            float2 a = unpack_h2(t.x), bb = unpack_h2(t.y);
            w[m] = make_float4(a.x, a.y, bb.x, bb.y);
        }
#pragma unroll
        for (int t = 0; t < 4; ++t) {
            const float C = c[5 + t], SV = sv[5 + t];
            const int msk = 1 << t;
#pragma unroll
            for (int m = 0; m < 16; ++m)
                if (!(m & msk)) bfly4(C, SV, w[m], w[m | msk]);
        }
#pragma unroll
        for (int m = 0; m < 16; ++m) {
            int h = (m << 5) | hl;
            uint2 t;
            t.x = pack_h2(w[m].x, w[m].y);
            t.y = pack_h2(w[m].z, w[m].w);
            *(uint2*)&buf[ppair(h, j)] = t;
        }
    }
    __syncthreads();

    // Stage B1: h bits 0..4 (qubits 8..4), regs r in [0,32), fp32 store
    {
        const int hh = tid >> 4;                    // h bits 5..8
        const int ll = tid & 15;                    // low offset
        const int q = ll >> 1, wd = ll & 1;
        float2 v[32];
#pragma unroll
        for (int r = 0; r < 32; ++r) {
            int h = (hh << 5) | r;
            v[r] = unpack_h2(buf[ppair(h, q) + wd]);
        }
#pragma unroll
        for (int t = 0; t < 5; ++t) {
            const float C = c[t], SV = sv[t];
            const int msk = 1 << t;
#pragma unroll
            for (int r = 0; r < 32; ++r)
                if (!(r & msk)) bfly(C, SV, v[r], v[r | msk]);
        }
#pragma unroll
        for (int r = 0; r < 32; ++r) {
            int h = (hh << 5) | r;
            p[h * 2048 + ll] = v[r];                // 128 B contiguous per 16 lanes
        }
    }
}

// ---------------------------------------------------------------------------
// Fallback (R0 verbatim, inline trig, no ws needed).
// ---------------------------------------------------------------------------
__global__ __launch_bounds__(64) void rx_pass1(
        const float* __restrict__ phi, const float* __restrict__ thetas,
        float2* __restrict__ out) {
    __shared__ float2 lds[2048];
    const int lane = threadIdx.x;
    const int W = blockIdx.x;
    const int b = W >> 9;
    const int base = (W & 511) << 11;
    const float* ph = phi + ((size_t)b << NQ) + base;
    float2* op = out + ((size_t)b << NQ) + base;

    float c[11], sv[11];
#pragma unroll
    for (int beta = 0; beta < 11; ++beta) {
        float th = 0.5f * thetas[b * NQ + (NQ - 1 - beta)];
        c[beta]  = bcast_first(cosf(th));
        sv[beta] = bcast_first(sinf(th));
    }

    float2 v[32];
#pragma unroll
    for (int k4 = 0; k4 < 8; ++k4) {
        float4 t = *(const float4*)(ph + (k4 << 8) + (lane << 2));
        v[k4 * 4 + 0] = make_float2(t.x, 0.f);
        v[k4 * 4 + 1] = make_float2(t.y, 0.f);
        v[k4 * 4 + 2] = make_float2(t.z, 0.f);
        v[k4 * 4 + 3] = make_float2(t.w, 0.f);
    }

    const int regbit1[5]  = {0, 1, 8, 9, 10};
    const int regmask1[5] = {1, 2, 4, 8, 16};
#pragma unroll
    for (int t = 0; t < 5; ++t) {
        const float C = c[regbit1[t]], SV = sv[regbit1[t]];
        const int m = regmask1[t];
#pragma unroll
        for (int r = 0; r < 32; ++r)
            if (!(r & m)) bfly(C, SV, v[r], v[r | m]);
    }

#pragma unroll
    for (int k4 = 0; k4 < 8; ++k4) {
        int low0 = (k4 << 8) + (lane << 2);
        int s0 = swz1(low0);
        *(float4*)&lds[s0]     = make_float4(v[k4*4+0].x, v[k4*4+0].y, v[k4*4+1].x, v[k4*4+1].y);
        *(float4*)&lds[s0 + 2] = make_float4(v[k4*4+2].x, v[k4*4+2].y, v[k4*4+3].x, v[k4*4+3].y);
    }
    __syncthreads();

    {
        const int g = lane >> 2, lam = lane & 3;
        float2 w2[32];
#pragma unroll
        for (int r = 0; r < 32; ++r) {
            int l = (g << 7) | (r << 2) | lam;
            w2[r] = lds[swz1(l)];
        }
#pragma unroll
        for (int t = 0; t < 5; ++t) {
            const float C = c[2 + t], SV = sv[2 + t];
            const int m = 1 << t;
#pragma unroll
            for (int r = 0; r < 32; ++r)
                if (!(r & m)) bfly(C, SV, w2[r], w2[r | m]);
        }
#pragma unroll
        for (int r = 0; r < 32; ++r) {
            int l = (g << 7) | (r << 2) | lam;
            lds[swz1(l)] = w2[r];
        }
    }
    __syncthreads();

    float4 u[16];
#pragma unroll
    for (int m = 0; m < 16; ++m) {
        int l0 = (lane << 1) | ((m & 1) << 7) | (((m >> 1) & 1) << 8)
               | (((m >> 2) & 1) << 9) | (((m >> 3) & 1) << 10);
        u[m] = *(float4*)&lds[swz1(l0)];
    }
    {
        const float C = c[7], SV = sv[7];
#pragma unroll
        for (int m = 0; m < 16; m += 2) {
            float4 A = u[m], B = u[m + 1];
            u[m]     = make_float4(C*A.x + SV*B.y, C*A.y - SV*B.x, C*A.z + SV*B.w, C*A.w - SV*B.z);
            u[m + 1] = make_float4(C*B.x + SV*A.y, C*B.y - SV*A.x, C*B.z + SV*A.w, C*B.w - SV*A.z);
        }
    }
#pragma unroll
    for (int m = 0; m < 16; ++m) {
        int l0 = (lane << 1) | ((m & 1) << 7) | (((m >> 1) & 1) << 8)
               | (((m >> 2) & 1) << 9) | (((m >> 3) & 1) << 10);
        *(float4*)(op + l0) = u[m];
    }
}

__device__ __forceinline__ int ppos(int h, int q) {
    return (h << 4) + (((q ^ (h & 7) ^ ((h >> 5) & 7)) & 7) << 1);
}

__global__ __launch_bounds__(256) void rx_pass2(
        const float* __restrict__ thetas, float2* __restrict__ out) {
    __shared__ float2 buf[8192];
    const int tid = threadIdx.x;
    const int b = blockIdx.x >> 7;
    const int lb = blockIdx.x & 127;
    float2* p = out + ((size_t)b << NQ) + (lb << 4);

    float c[9], sv[9];
#pragma unroll
    for (int i = 0; i < 9; ++i) {
        float th = 0.5f * thetas[b * NQ + (8 - i)];
        c[i]  = bcast_first(cosf(th));
        sv[i] = bcast_first(sinf(th));
    }

#pragma unroll
    for (int i = 0; i < 16; ++i) {
        int f = (i << 8) | tid;
        int h = f >> 3, j = f & 7;
        float4 t = *(const float4*)(p + h * 2048 + (j << 1));
        *(float4*)&buf[ppos(h, j)] = t;
    }
    __syncthreads();

    {
        const int hl = tid & 31;
        const int j  = tid >> 5;
        float4 w[16];
#pragma unroll
        for (int m = 0; m < 16; ++m)
            w[m] = *(float4*)&buf[ppos((m << 5) | hl, j)];
#pragma unroll
        for (int t = 0; t < 4; ++t) {
            const float C = c[5 + t], SV = sv[5 + t];
            const int msk = 1 << t;
#pragma unroll
            for (int m = 0; m < 16; ++m)
                if (!(m & msk)) bfly4(C, SV, w[m], w[m | msk]);
        }
#pragma unroll
        for (int m = 0; m < 16; ++m)
            *(float4*)&buf[ppos((m << 5) | hl, j)] = w[m];
    }
    __syncthreads();

    {
        const int hh = tid >> 4;
        const int ll = tid & 15;
        float2 v[32];
#pragma unroll
        for (int r = 0; r < 32; ++r) {
            int h = (hh << 5) | r;
            v[r] = buf[ppos(h, ll >> 1) + (ll & 1)];
        }
#pragma unroll
        for (int t = 0; t < 5; ++t) {
            const float C = c[t], SV = sv[t];
            const int msk = 1 << t;
#pragma unroll
            for (int r = 0; r < 32; ++r)
                if (!(r & msk)) bfly(C, SV, v[r], v[r | msk]);
        }
#pragma unroll
        for (int r = 0; r < 32; ++r) {
            int h = (hh << 5) | r;
            p[h * 2048 + ll] = v[r];
        }
    }
}

extern "C" void kernel_launch(void* const* d_in, const int* in_sizes, int n_in,
                              void* d_out, int out_size, void* d_ws, size_t ws_size,
                              hipStream_t stream) {
    const float* phi    = (const float*)d_in[0];
    const float* thetas = (const float*)d_in[1];
    float2* out = (float2*)d_out;
    if (d_ws != nullptr && ws_size >= 16 * NQ * sizeof(float2)) {
        float2* tab = (float2*)d_ws;
        rx_trig<<<1, 320, 0, stream>>>(thetas, tab);
        rx_p1<<<8192, 64, 0, stream>>>(phi, tab, out);
        rx_p2<<<2048, 256, 0, stream>>>(tab, out);
    } else {
        rx_pass1<<<8192, 64, 0, stream>>>(phi, thetas, out);
        rx_pass2<<<2048, 256, 0, stream>>>(thetas, out);
    }
}